// Round 6
// baseline (305.446 us; speedup 1.0000x reference)
//
#include <hip/hip_runtime.h>
#include <stdint.h>

typedef unsigned short u16;
typedef __attribute__((ext_vector_type(4))) unsigned short u16x4;
typedef __attribute__((ext_vector_type(8))) unsigned short u16x8;
typedef __attribute__((ext_vector_type(8))) __bf16 bf16x8;
typedef __attribute__((ext_vector_type(2))) _Float16 half2;
typedef __attribute__((ext_vector_type(8))) _Float16 half8;
typedef __attribute__((ext_vector_type(4))) float f32x4;
typedef __attribute__((ext_vector_type(4))) uint32_t u32x4;

#define SEQ 2048
#define DM 1024
#define NH 16
#define DH 64
#define BATCH 4
#define MROWS (BATCH * SEQ)  // 8192
#define KT64 (DM / 64)       // 16 K-tiles of 64

// 0.125 (= Dh^-0.5) * log2(e): folded into the Q projection so S^T comes out
// of the MFMA already in log2 units.
#define SC_LOG2E 0.18033688011112042f

__device__ __forceinline__ u16 f2bf(float f) {
    uint32_t u = __builtin_bit_cast(uint32_t, f);
    u += 0x7fffu + ((u >> 16) & 1u);   // RNE
    return (u16)(u >> 16);
}
__device__ __forceinline__ u16 f2h(float f) {
    return __builtin_bit_cast(u16, (_Float16)f);
}
__device__ __forceinline__ half2 pkrtz(float a, float b) {
    return __builtin_bit_cast(half2, __builtin_amdgcn_cvt_pkrtz(a, b));
}

__device__ __forceinline__ void load16_lds(const void* g, void* l) {
    __builtin_amdgcn_global_load_lds(
        (const __attribute__((address_space(1))) uint32_t*)(uintptr_t)g,
        (__attribute__((address_space(3))) uint32_t*)(uintptr_t)l,
        16, 0, 0);
}

// ---------------- fp32 -> bf16 convert: WEIGHTS ONLY now ----------------
#define N4W (DM * DM / 4)     // 262144

__device__ __forceinline__ void cvt_one(const float* src, u16* dst, int i) {
    float4 v = ((const float4*)src)[i];
    u16x4 o;
    o[0] = f2bf(v.x); o[1] = f2bf(v.y); o[2] = f2bf(v.z); o[3] = f2bf(v.w);
    *(u16x4*)(dst + (size_t)i * 4) = o;
}

__global__ void cvt_w(const float* __restrict__ w0, const float* __restrict__ w1,
                      const float* __restrict__ w2, const float* __restrict__ w3,
                      u16* __restrict__ d0, u16* __restrict__ d1,
                      u16* __restrict__ d2, u16* __restrict__ d3) {
    int i = blockIdx.x * 256 + threadIdx.x;   // [0, 4*N4W)
    int s = i >> 18;            // 0..3 (N4W = 2^18)
    int l = i & (N4W - 1);
    const float* src = s == 0 ? w0 : s == 1 ? w1 : s == 2 ? w2 : w3;
    u16* dst = s == 0 ? d0 : s == 1 ? d1 : s == 2 ? d2 : d3;
    cvt_one(src, dst, l);
}

// ---------------- fused QKV GEMM: fp32-A reg-cvt staging ----------------
// 128x128 tile, BK=64, 4 waves (2x2, 64x64/wave), 2-buffer LDS 64 KiB ->
// 2 blocks/CU (r4's proven residency/protocol). A comes straight from the
// fp32 activations: per kt, 8 global dwordx4 (issued 2 kt ahead into
// alternating reg sets) -> 16 v_cvt_pk_bf16_f32 (RNE, identical to f2bf) ->
// 4 ds_write_b128 (swizzled; 8 lanes/4-bank-group = conflict-free minimum).
// B (bf16 weights) keeps the r4 global_load_lds path.
// FIFO protocol (B pinned before A-loads by sched_barrier(0)):
//   kt: issue B4(kt+1)->buf^1, A8(kt+2)->rnext; [compiler auto-vmcnt
//   before cvt retires rcur=A(kt+1), leaving {B4,A8}]; cvt+write rcur->
//   buf^1; ds_read frags(buf b)+32 MFMA; lgkmcnt(0); vmcnt(8) retires B4
//   exactly (A8 stays in flight); barrier. Tail: vmcnt(0).
#define QBUF 16384   // u16 per buffer: A [0,8192) + B [8192,16384)

__global__ __launch_bounds__(256, 2) void qkv_gemm(const float* __restrict__ qf,
                                                   const float* __restrict__ kvf,
                                                   const u16* __restrict__ wq,
                                                   const u16* __restrict__ wk,
                                                   const u16* __restrict__ wv,
                                                   u16* __restrict__ Qh,
                                                   u16* __restrict__ Kh,
                                                   u16* __restrict__ Vt) {
    __shared__ __align__(16) u16 lds[2 * QBUF];   // 64 KiB
    const int g = blockIdx.x;
    const int xcd = g & 7, l = g >> 3;          // l in [0,192)
    const int mt = xcd * 8 + (l & 7);           // 0..63
    const int pn = l >> 3;                      // 0..23
    const int sel = pn >> 3;                    // 0=Q 1=K 2=V
    const int m0 = mt * 128, n0 = (pn & 7) * 128;
    const float* Af = (sel == 0) ? qf : kvf;
    const u16* Bg = (sel == 0) ? wq : (sel == 1 ? wk : wv);

    const int t = threadIdx.x;
    const int lane = t & 63, w = t >> 6;
    const int ln = lane & 15, quad = lane >> 4;
    const int wrow = (w >> 1) * 64, wcol = (w & 1) * 64;

    // A fp32 source: thread t owns row t>>1, k-half (t&1)*32 (32 floats/kt)
    const float* Ath = Af + (size_t)(m0 + (t >> 1)) * DM + (t & 1) * 32;
    const int arow = t >> 1;
    const int acj0 = (t & 1) * 4;               // first of 4 bf16 16B-chunks

    auto stageB = [&](int kt, int b) {
#pragma unroll
        for (int i = 0; i < 4; ++i) {
            const int u = i * 256 + t;          // 1024 units (16 KB)
            const int row = u >> 3, c = u & 7;
            load16_lds(Bg + (size_t)(n0 + row) * DM + kt * 64 + ((c ^ (row & 7)) << 3),
                       &lds[b * QBUF + 8192 + u * 8]);
        }
    };
    auto loadA = [&](f32x4 (&r)[8], int kt) {
#pragma unroll
        for (int j = 0; j < 8; ++j)
            r[j] = *(const f32x4*)(Ath + kt * 64 + j * 4);
    };
    auto cvtwrite = [&](const f32x4 (&r)[8], int b) {
#pragma unroll
        for (int c4 = 0; c4 < 4; ++c4) {
            uint32_t w0, w1, w2, w3;
            asm("v_cvt_pk_bf16_f32 %0, %1, %2" : "=v"(w0) : "v"(r[2 * c4][0]), "v"(r[2 * c4][1]));
            asm("v_cvt_pk_bf16_f32 %0, %1, %2" : "=v"(w1) : "v"(r[2 * c4][2]), "v"(r[2 * c4][3]));
            asm("v_cvt_pk_bf16_f32 %0, %1, %2" : "=v"(w2) : "v"(r[2 * c4 + 1][0]), "v"(r[2 * c4 + 1][1]));
            asm("v_cvt_pk_bf16_f32 %0, %1, %2" : "=v"(w3) : "v"(r[2 * c4 + 1][2]), "v"(r[2 * c4 + 1][3]));
            u32x4 q = {w0, w1, w2, w3};
            const int cj = acj0 + c4;
            *(u32x4*)&lds[b * QBUF + arow * 64 + ((cj ^ (arow & 7)) << 3)] = q;
        }
    };
    auto rdA = [&](int b, int ks, int mi) -> bf16x8 {
        const int row = wrow + mi * 16 + ln;
        return __builtin_bit_cast(bf16x8, *(const u16x8*)&lds[
            b * QBUF + row * 64 + (((ks * 4 + quad) ^ (row & 7)) << 3)]);
    };
    auto rdB = [&](int b, int ks, int nj) -> bf16x8 {
        const int row = wcol + nj * 16 + ln;
        return __builtin_bit_cast(bf16x8, *(const u16x8*)&lds[
            b * QBUF + 8192 + row * 64 + (((ks * 4 + quad) ^ (row & 7)) << 3)]);
    };

    f32x4 acc[4][4] = {};
    f32x4 rA0[8], rA1[8];

    // prologue: B(0)->buf0; A(0)->tmp; A(1)->rA0; cvt tmp->buf0.
    stageB(0, 0);
    __builtin_amdgcn_sched_barrier(0);
    {
        f32x4 atmp[8];
        loadA(atmp, 0);
        loadA(rA0, 1);
        cvtwrite(atmp, 0);   // compiler auto-vmcnt retires atmp (and B4(0))
    }
    asm volatile("s_waitcnt lgkmcnt(0)" ::: "memory");
    __builtin_amdgcn_s_barrier();

    auto body = [&](int kt, int b, f32x4 (&rcur)[8], f32x4 (&rnext)[8]) {
        if (kt < KT64 - 1) {
            stageB(kt + 1, b ^ 1);
            __builtin_amdgcn_sched_barrier(0);   // pin B before A in VMEM FIFO
        }
        if (kt < KT64 - 2) loadA(rnext, kt + 2);
        if (kt < KT64 - 1) cvtwrite(rcur, b ^ 1);
#pragma unroll
        for (int ks = 0; ks < 2; ++ks) {
            bf16x8 af[4], bf[4];
#pragma unroll
            for (int mi = 0; mi < 4; ++mi) af[mi] = rdA(b, ks, mi);
#pragma unroll
            for (int nj = 0; nj < 4; ++nj) bf[nj] = rdB(b, ks, nj);
            __builtin_amdgcn_s_setprio(1);
#pragma unroll
            for (int mi = 0; mi < 4; ++mi)
#pragma unroll
                for (int nj = 0; nj < 4; ++nj)
                    acc[mi][nj] = __builtin_amdgcn_mfma_f32_16x16x32_bf16(
                        af[mi], bf[nj], acc[mi][nj], 0, 0, 0);
            __builtin_amdgcn_s_setprio(0);
        }
        asm volatile("s_waitcnt lgkmcnt(0)" ::: "memory");
        if (kt < KT64 - 2) { asm volatile("s_waitcnt vmcnt(8)" ::: "memory"); }
        else               { asm volatile("s_waitcnt vmcnt(0)" ::: "memory"); }
        __builtin_amdgcn_s_barrier();
    };
    for (int k2 = 0; k2 < KT64; k2 += 2) {
        body(k2, 0, rA0, rA1);
        body(k2 + 1, 1, rA1, rA0);
    }

    if (sel == 2) {  // V: f16 transposed store Vt[(b*NH+h)*DH+d][S]
#pragma unroll
        for (int mi = 0; mi < 4; ++mi) {
            int rowb = m0 + wrow + mi * 16 + quad * 4;
            int bb = rowb >> 11, s = rowb & 2047;
#pragma unroll
            for (int ni = 0; ni < 4; ++ni) {
                int col = n0 + wcol + ni * 16 + ln;
                int h = col >> 6, d = col & 63;
                u16x4 o;
#pragma unroll
                for (int r = 0; r < 4; ++r) o[r] = f2h(acc[mi][ni][r]);
                *(u16x4*)(Vt + ((size_t)(bb * NH + h) * DH + d) * SEQ + s) = o;
            }
        }
    } else {  // Q/K: bf16 scatter to [B,H,S,Dh]; Q pre-scaled by SC_LOG2E
        u16* C = sel ? Kh : Qh;
        const float scale = sel ? 1.0f : SC_LOG2E;
#pragma unroll
        for (int mi = 0; mi < 4; ++mi) {
            int rowb = m0 + wrow + mi * 16 + quad * 4;
#pragma unroll
            for (int ni = 0; ni < 4; ++ni) {
                int col = n0 + wcol + ni * 16 + ln;
                int h = col >> 6, d = col & 63;
#pragma unroll
                for (int r = 0; r < 4; ++r) {
                    int row = rowb + r;
                    int bb = row >> 11, s = row & 2047;
                    C[((size_t)((bb * NH + h) * SEQ + s) << 6) + d] = f2bf(acc[mi][ni][r] * scale);
                }
            }
        }
    }
}

// ---------------- r4 GEMM core (bf16 A+B via global_load_lds) for wo ------
__device__ __forceinline__ void gcore128(const u16* __restrict__ Ag,
                                         const u16* __restrict__ Bg,
                                         int m0, int n0, f32x4 (&acc)[4][4]) {
    constexpr int BUF = 128 * 64 * 2;   // u16 per buffer (A + B)
    __shared__ __align__(16) u16 lds[2 * BUF];   // 64 KiB
    const int t = threadIdx.x;
    const int lane = t & 63, w = t >> 6;
    const int ln = lane & 15, quad = lane >> 4;
    const int wrow = (w >> 1) * 64, wcol = (w & 1) * 64;

    auto stage = [&](int kt, int b) {
        if (kt >= KT64) kt = KT64 - 1;   // tail: rewrites dead buffer, benign
#pragma unroll
        for (int i = 0; i < 8; ++i) {
            const int u = i * 256 + t;          // 16B unit index
            const int isB = u >> 10;
            const int v = u & 1023;
            const int row = v >> 3, c = v & 7;
            const u16* base = isB ? Bg : Ag;
            const int g0 = (isB ? n0 : m0) + row;
            load16_lds(base + (size_t)g0 * DM + kt * 64 + ((c ^ (row & 7)) << 3),
                       &lds[(size_t)b * BUF + (size_t)u * 8]);
        }
    };
    auto rdA = [&](int b, int ks, int mi) -> bf16x8 {
        const int row = wrow + mi * 16 + ln;
        return __builtin_bit_cast(bf16x8, *(const u16x8*)&lds[
            (size_t)b * BUF + row * 64 + (((ks * 4 + quad) ^ (row & 7)) << 3)]);
    };
    auto rdB = [&](int b, int ks, int nj) -> bf16x8 {
        const int row = wcol + nj * 16 + ln;
        return __builtin_bit_cast(bf16x8, *(const u16x8*)&lds[
            (size_t)b * BUF + 8192 + row * 64 + (((ks * 4 + quad) ^ (row & 7)) << 3)]);
    };

    stage(0, 0);
    asm volatile("s_waitcnt vmcnt(0)" ::: "memory");
    __builtin_amdgcn_s_barrier();

    for (int kt = 0; kt < KT64; ++kt) {
        const int b = kt & 1;
        stage(kt + 1, b ^ 1);   // earliest possible issue -> max latency cover
#pragma unroll
        for (int ks = 0; ks < 2; ++ks) {
            bf16x8 af[4], bf[4];
#pragma unroll
            for (int mi = 0; mi < 4; ++mi) af[mi] = rdA(b, ks, mi);
#pragma unroll
            for (int nj = 0; nj < 4; ++nj) bf[nj] = rdB(b, ks, nj);
            __builtin_amdgcn_s_setprio(1);
#pragma unroll
            for (int mi = 0; mi < 4; ++mi)
#pragma unroll
                for (int nj = 0; nj < 4; ++nj)
                    acc[mi][nj] = __builtin_amdgcn_mfma_f32_16x16x32_bf16(
                        af[mi], bf[nj], acc[mi][nj], 0, 0, 0);
            __builtin_amdgcn_s_setprio(0);
        }
        asm volatile("s_waitcnt vmcnt(0)" ::: "memory");  // kt+1 landed
        __builtin_amdgcn_s_barrier();
    }
}

// ---------------- output projection GEMM (fp32 out) ----------------
__global__ __launch_bounds__(256, 2) void wo_gemm(const u16* __restrict__ A,
                                                  const u16* __restrict__ B,
                                                  float* __restrict__ Cout) {
    const int g = blockIdx.x;
    const int xcd = g & 7, l = g >> 3;          // l in [0,64)
    const int mt = xcd * 8 + (l & 7);           // 0..63
    const int nt = l >> 3;                      // 0..7
    const int m0 = mt * 128, n0 = nt * 128;

    f32x4 acc[4][4] = {};
    gcore128(A, B, m0, n0, acc);

    const int t = threadIdx.x;
    const int lane = t & 63, w = t >> 6;
    const int ln = lane & 15, quad = lane >> 4;
    const int wrow = (w >> 1) * 64, wcol = (w & 1) * 64;

#pragma unroll
    for (int mi = 0; mi < 4; ++mi) {
        int rowb = m0 + wrow + mi * 16 + quad * 4;
#pragma unroll
        for (int ni = 0; ni < 4; ++ni) {
            int col = n0 + wcol + ni * 16 + ln;
#pragma unroll
            for (int r = 0; r < 4; ++r)
                Cout[(size_t)(rowb + r) * DM + col] = acc[mi][ni][r];
        }
    }
}

// ---------------- flash attention v5 (unchanged) ----------------
__global__ __launch_bounds__(256) void attn_kernel(const u16* __restrict__ Q,
                                                   const u16* __restrict__ K,
                                                   const u16* __restrict__ Vt,
                                                   u16* __restrict__ AO) {
    __shared__ __align__(16) u16 qs[128 * 64];  // [q][d] swizzled, 16 KB
    __shared__ __align__(16) u16 ks[64 * 64];   // [kv-permuted][d] swizzled, 8 KB
    __shared__ __align__(16) u16 vs[80 * 64];   // [d][kv] f16; rows 64-79 const, 10 KB

    const int t = threadIdx.x;
    const int lane = t & 63, w = t >> 6;
    const int ln = lane & 15, quad = lane >> 4;
    const int l3 = ln & 7;
    const int bi = blockIdx.x;            // 0..1023
    const int bh = bi & 63;
    const int qraw = bi >> 6;             // 0..15
    const int qtile = (bh & 1) ? (15 - qraw) : qraw;  // balance swizzle
    const int q0 = qtile * 128;
    const int qw0 = q0 + w * 32;
    const int ktmax = 2 * qtile + 1;
    const u16* Qb = Q + (size_t)bh * SEQ * DH;
    const u16* Kb = K + (size_t)bh * SEQ * DH;
    const u16* Vb = Vt + (size_t)bh * DH * SEQ;
    const int b = bh >> 4, h = bh & 15;

    const int cb = t & 7;          // staging col-block
    const int r0 = t >> 3;         // staging row base (0..31)
    const int swc = ((cb ^ (r0 & 7)) << 3);
    // K source-row permutation sigma(r0): bits [b4 b3 b2 b1 b0]->[b3 b2 b4 b1 b0]
    const int sg = ((r0 & 12) << 1) | ((r0 & 16) >> 2) | (r0 & 3);

    // const rows 64..79 of vs: row 64 = 1.0h (l-row), rest 0. Written once.
    if (t < 128) {
        int j = t >> 3;            // 0..15
        u16 hv = (j == 0) ? 0x3C00 : 0;
        u16x8 o = {hv, hv, hv, hv, hv, hv, hv, hv};
        *(u16x8*)&vs[((64 + j) << 6) | (((t & 7) ^ (j & 7)) << 3)] = o;
    }

    // prefetch Q tile + KV tile 0 into regs (K rows permuted by sigma)
    u16x8 qreg[4];
#pragma unroll
    for (int i = 0; i < 4; ++i)
        qreg[i] = *(const u16x8*)(Qb + (size_t)(q0 + r0 + i * 32) * DH + cb * 8);
    u16x8 kreg[2], vreg[2];
#pragma unroll
    for (int i = 0; i < 2; ++i) {
        kreg[i] = *(const u16x8*)(Kb + (size_t)(i * 32 + sg) * DH + cb * 8);
        vreg[i] = *(const u16x8*)(Vb + (size_t)(r0 + i * 32) * SEQ + cb * 8);
    }

    f32x4 oaccT[2][5] = {};

    for (int kt = 0; kt <= ktmax; ++kt) {
        const int kv0 = kt * 64;
        __syncthreads();  // all waves done reading previous tile
        if (kt == 0) {
#pragma unroll
            for (int i = 0; i < 4; ++i)
                *(u16x8*)&qs[((r0 + i * 32) << 6) | swc] = qreg[i];
        }
#pragma unroll
        for (int i = 0; i < 2; ++i) {
            *(u16x8*)&ks[((r0 + i * 32) << 6) | swc] = kreg[i];
            *(u16x8*)&vs[((r0 + i * 32) << 6) | swc] = vreg[i];
        }
        __syncthreads();  // tile published
        if (kt < ktmax) {
            const int kvn = kv0 + 64;
#pragma unroll
            for (int i = 0; i < 2; ++i) {
                kreg[i] = *(const u16x8*)(Kb + (size_t)(kvn + i * 32 + sg) * DH + cb * 8);
                vreg[i] = *(const u16x8*)(Vb + (size_t)(r0 + i * 32) * SEQ + kvn + cb * 8);
            }
        }

        if (kv0 >= qw0 + 32) continue;  // wave-uniform; barriers already done

        // ---- S^T = K Q^T : C[m=permuted kv][n=q] ----
        f32x4 st[2][4] = {};
#pragma unroll
        for (int half = 0; half < 2; ++half) {
            const int swz = (((half * 4 + quad) ^ l3) << 3);
            bf16x8 qf0 = __builtin_bit_cast(bf16x8, *(const u16x8*)&qs[((w * 32 + ln) << 6) | swz]);
            bf16x8 qf1 = __builtin_bit_cast(bf16x8, *(const u16x8*)&qs[((w * 32 + 16 + ln) << 6) | swz]);
#pragma unroll
            for (int ms = 0; ms < 4; ++ms) {
                bf16x8 kf = __builtin_bit_cast(bf16x8, *(const u16x8*)&ks[((ms * 16 + ln) << 6) | swz]);
                st[0][ms] = __builtin_amdgcn_mfma_f32_16x16x32_bf16(kf, qf0, st[0][ms], 0, 0, 0);
                st[1][ms] = __builtin_amdgcn_mfma_f32_16x16x32_bf16(kf, qf1, st[1][ms], 0, 0, 0);
            }
        }

        // ---- P = exp2(S^T); lane's value (ms,r) sits at true kv =
        //      kv0 + (ms>>1)*32 + quad*8 + (ms&1)*4 + r (sigma-permuted) ----
        half8 pf[2][2];
#pragma unroll
        for (int qt2 = 0; qt2 < 2; ++qt2) {
            const int qbase = qw0 + qt2 * 16;       // lane's q = qbase + ln
            if (kv0 + 63 > qbase) {                 // diagonal tile (wave-uniform)
                const int relq = qbase + ln - kv0 - quad * 8;
#pragma unroll
                for (int ms = 0; ms < 4; ++ms)
#pragma unroll
                    for (int r = 0; r < 4; ++r)
                        if ((ms >> 1) * 32 + (ms & 1) * 4 + r > relq)
                            st[qt2][ms][r] = -3e38f;
            }
#pragma unroll
            for (int c = 0; c < 2; ++c) {
                half2 p0 = pkrtz(__builtin_amdgcn_exp2f(st[qt2][2 * c][0]),
                                 __builtin_amdgcn_exp2f(st[qt2][2 * c][1]));
                half2 p1 = pkrtz(__builtin_amdgcn_exp2f(st[qt2][2 * c][2]),
                                 __builtin_amdgcn_exp2f(st[qt2][2 * c][3]));
                half2 p2 = pkrtz(__builtin_amdgcn_exp2f(st[qt2][2 * c + 1][0]),
                                 __builtin_amdgcn_exp2f(st[qt2][2 * c + 1][1]));
                half2 p3 = pkrtz(__builtin_amdgcn_exp2f(st[qt2][2 * c + 1][2]),
                                 __builtin_amdgcn_exp2f(st[qt2][2 * c + 1][3]));
                half8 v;
                v[0] = p0[0]; v[1] = p0[1]; v[2] = p1[0]; v[3] = p1[1];
                v[4] = p2[0]; v[5] = p2[1]; v[6] = p3[0]; v[7] = p3[1];
                pf[qt2][c] = v;
            }
        }

        // ---- O^T += V^T P^T : 16x16x32_f16, A = V^T (b128 from LDS),
        //      B = P (in-lane frags); nd=4 accumulates l via the ones-row ----
#pragma unroll
        for (int c = 0; c < 2; ++c) {
            const int off = (((c * 4 + quad) ^ l3) << 3);
#pragma unroll
            for (int nd = 0; nd < 5; ++nd) {
                half8 vf = __builtin_bit_cast(half8, *(const u16x8*)&vs[((nd * 16 + ln) << 6) | off]);
                oaccT[0][nd] = __builtin_amdgcn_mfma_f32_16x16x32_f16(vf, pf[0][c], oaccT[0][nd], 0, 0, 0);
                oaccT[1][nd] = __builtin_amdgcn_mfma_f32_16x16x32_f16(vf, pf[1][c], oaccT[1][nd], 0, 0, 0);
            }
        }
    }

    // epilogue: O^T rows = d, cols = q (= ln); l sits in quad 0's
    // oaccT[qt2][4][0] (vs row 64).
#pragma unroll
    for (int qt2 = 0; qt2 < 2; ++qt2) {
        float lv = __shfl(oaccT[qt2][4][0], ln, 64);
        float linv = 1.0f / lv;
        int q = q0 + w * 32 + qt2 * 16 + ln;
        size_t base = ((size_t)(b * SEQ + q) * DM) + h * DH + quad * 4;
#pragma unroll
        for (int nd = 0; nd < 4; ++nd) {
            u16x4 o;
#pragma unroll
            for (int r = 0; r < 4; ++r) o[r] = f2bf(oaccT[qt2][nd][r] * linv);
            *(u16x4*)&AO[base + nd * 16] = o;
        }
    }
}

// ---------------- launch ----------------
extern "C" void kernel_launch(void* const* d_in, const int* in_sizes, int n_in,
                              void* d_out, int out_size, void* d_ws, size_t ws_size,
                              hipStream_t stream) {
    const float* query = (const float*)d_in[0];
    const float* key_value = (const float*)d_in[1];
    const float* Wq = (const float*)d_in[2];
    const float* Wk = (const float*)d_in[3];
    const float* Wv = (const float*)d_in[4];
    const float* Wo = (const float*)d_in[5];
    float* out = (float*)d_out;

    char* ws = (char*)d_ws;
    const size_t SZ_ACT = (size_t)MROWS * DM * 2;  // 16 MiB
    const size_t SZ_W = (size_t)DM * DM * 2;       // 2 MiB
    u16* AOb   = (u16*)(ws + 0);                   // attn output, bf16
    u16* wq_bf = (u16*)(ws + 2 * SZ_ACT);
    u16* wk_bf = (u16*)(ws + 2 * SZ_ACT + SZ_W);
    u16* wv_bf = (u16*)(ws + 2 * SZ_ACT + 2 * SZ_W);
    u16* wo_bf = (u16*)(ws + 2 * SZ_ACT + 3 * SZ_W);
    u16* Qh    = (u16*)(ws + 2 * SZ_ACT + 4 * SZ_W);              // [B,H,S,Dh] bf16 (pre-scaled)
    u16* Kh    = (u16*)(ws + 2 * SZ_ACT + 4 * SZ_W + SZ_ACT);     // [B,H,S,Dh] bf16
    u16* Vt    = (u16*)(ws + 2 * SZ_ACT + 4 * SZ_W + 2 * SZ_ACT); // [bh][64][S] f16

    cvt_w<<<4 * N4W / 256, 256, 0, stream>>>(Wq, Wk, Wv, Wo,
                                             wq_bf, wk_bf, wv_bf, wo_bf);

    qkv_gemm<<<1536, 256, 0, stream>>>(query, key_value, wq_bf, wk_bf, wv_bf,
                                       Qh, Kh, Vt);

    attn_kernel<<<1024, 256, 0, stream>>>(Qh, Kh, Vt, AOb);

    wo_gemm<<<512, 256, 0, stream>>>(AOb, wo_bf, out);
}

// Round 7
// 267.041 us; speedup vs baseline: 1.1438x; 1.1438x over previous
//
#include <hip/hip_runtime.h>
#include <stdint.h>

typedef unsigned short u16;
typedef __attribute__((ext_vector_type(4))) unsigned short u16x4;
typedef __attribute__((ext_vector_type(8))) unsigned short u16x8;
typedef __attribute__((ext_vector_type(8))) __bf16 bf16x8;
typedef __attribute__((ext_vector_type(2))) _Float16 half2;
typedef __attribute__((ext_vector_type(8))) _Float16 half8;
typedef __attribute__((ext_vector_type(4))) float f32x4;

#define SEQ 2048
#define DM 1024
#define NH 16
#define DH 64
#define BATCH 4
#define MROWS (BATCH * SEQ)  // 8192
#define KT32 (DM / 32)       // 32 K-tiles of 32

// 0.125 (= Dh^-0.5) * log2(e): folded into the Q projection so S^T comes out
// of the MFMA already in log2 units.
#define SC_LOG2E 0.18033688011112042f

__device__ __forceinline__ u16 f2bf(float f) {
    uint32_t u = __builtin_bit_cast(uint32_t, f);
    u += 0x7fffu + ((u >> 16) & 1u);   // RNE
    return (u16)(u >> 16);
}
__device__ __forceinline__ u16 f2h(float f) {
    return __builtin_bit_cast(u16, (_Float16)f);
}
__device__ __forceinline__ half2 pkrtz(float a, float b) {
    return __builtin_bit_cast(half2, __builtin_amdgcn_cvt_pkrtz(a, b));
}

__device__ __forceinline__ void load16_lds(const void* g, void* l) {
    __builtin_amdgcn_global_load_lds(
        (const __attribute__((address_space(1))) uint32_t*)(uintptr_t)g,
        (__attribute__((address_space(3))) uint32_t*)(uintptr_t)l,
        16, 0, 0);
}

// ---------------- fp32 -> bf16 convert: ALL six tensors, one launch --------
#define N4A (MROWS * DM / 4)  // 2097152
#define N4W (DM * DM / 4)     // 262144

__device__ __forceinline__ void cvt_one(const float* src, u16* dst, int i) {
    float4 v = ((const float4*)src)[i];
    u16x4 o;
    o[0] = f2bf(v.x); o[1] = f2bf(v.y); o[2] = f2bf(v.z); o[3] = f2bf(v.w);
    *(u16x4*)(dst + (size_t)i * 4) = o;
}

__global__ void cvt_all(const float* __restrict__ q, const float* __restrict__ kv,
                        const float* __restrict__ w0, const float* __restrict__ w1,
                        const float* __restrict__ w2, const float* __restrict__ w3,
                        u16* __restrict__ dq, u16* __restrict__ dkv,
                        u16* __restrict__ dw0, u16* __restrict__ dw1,
                        u16* __restrict__ dw2, u16* __restrict__ dw3) {
    int i = blockIdx.x * 256 + threadIdx.x;
    if (i < N4A) { cvt_one(q, dq, i); return; }
    i -= N4A;
    if (i < N4A) { cvt_one(kv, dkv, i); return; }
    i -= N4A;
    int s = i >> 18;            // 0..3 (N4W = 2^18)
    int l = i & (N4W - 1);
    const float* src = s == 0 ? w0 : s == 1 ? w1 : s == 2 ? w2 : w3;
    u16* dst = s == 0 ? dw0 : s == 1 ? dw1 : s == 2 ? dw2 : dw3;
    cvt_one(src, dst, l);
}

// ------- 128x128 / BK=32 GEMM core, A prefetched 2 tiles ahead -------
// 256 threads = 4 waves (2Mx2N), per-wave 64x64, acc[4][4] f32x4.
// LDS: A triple-buffered (3 x 8 KB) + B double-buffered (2 x 8 KB) = 40 KB
// -> 4 blocks/CU (VGPR ~64, r5-measured). The A-distance-2 is the fix for
// the r4/r5 stall: A streams from HBM (~900 cyc); with 1-tile distance the
// end-of-kt wait ate uncovered latency every kt. Now A(kt+2) is issued at
// kt and only waited at the end of kt+1 (~2 bodies x 4-block interleave).
// B (weights, L2-resident across 64 m-blocks) keeps distance 1.
// FIFO per kt: issue B(kt+1) then A(kt+2); steady outstanding groups =
// [A(kt+1), B(kt+1), A(kt+2)] (2 loads each) -> vmcnt(2) retires exactly
// A(kt+1)+B(kt+1). Prologue [B0,A0,A1] -> vmcnt(2). Tail: kt=30 issues
// B31 only -> vmcnt(0); kt=31 issues nothing.
// Overwrite hazards: at kt, B(kt+1) targets buf (kt+1)&1 (read at kt-1,
// ds_reads retired at the kt-1 end barrier); A(kt+2) targets (kt+2)%3 =
// (kt-1)%3 (read at kt-1, same argument). Race-free.
// Swizzle (64 B rows, 4 chunks of 16 B): chunk' = chunk ^ ((row>>1)&3),
// r5-verified 0 bank conflicts; DMA dest linear, source pre-swizzled.
__device__ __forceinline__ void gcore(const u16* __restrict__ Ag,
                                      const u16* __restrict__ Bg,
                                      int m0, int n0, f32x4 (&acc)[4][4]) {
    __shared__ __align__(16) u16 lds[20480];   // A [0,12288) + B [12288,20480)
    const int t = threadIdx.x;
    const int lane = t & 63, w = t >> 6;
    const int ln = lane & 15, quad = lane >> 4;
    const int wrow = (w >> 1) * 64, wcol = (w & 1) * 64;

    // stage one 128x32 bf16 panel: 512 16B-units, 2 per thread.
    auto stageA = [&](int kt, int ab) {
#pragma unroll
        for (int i = 0; i < 2; ++i) {
            const int u = i * 256 + t;
            const int row = u >> 2, c = u & 3;
            load16_lds(Ag + (size_t)(m0 + row) * DM + kt * 32 + ((c ^ ((row >> 1) & 3)) << 3),
                       &lds[ab * 4096 + u * 8]);
        }
    };
    auto stageB = [&](int kt, int bb) {
#pragma unroll
        for (int i = 0; i < 2; ++i) {
            const int u = i * 256 + t;
            const int row = u >> 2, c = u & 3;
            load16_lds(Bg + (size_t)(n0 + row) * DM + kt * 32 + ((c ^ ((row >> 1) & 3)) << 3),
                       &lds[12288 + bb * 4096 + u * 8]);
        }
    };
    auto rdA = [&](int ab, int mi) -> bf16x8 {
        const int row = wrow + mi * 16 + ln;
        return __builtin_bit_cast(bf16x8, *(const u16x8*)&lds[
            ab * 4096 + row * 32 + ((quad ^ ((row >> 1) & 3)) << 3)]);
    };
    auto rdB = [&](int bb, int nj) -> bf16x8 {
        const int row = wcol + nj * 16 + ln;
        return __builtin_bit_cast(bf16x8, *(const u16x8*)&lds[
            12288 + bb * 4096 + row * 32 + ((quad ^ ((row >> 1) & 3)) << 3)]);
    };

    // prologue: B0, A0, A1 (FIFO order). vmcnt(2) retires B0+A0, A1 in flight.
    stageB(0, 0);
    stageA(0, 0);
    stageA(1, 1);
    asm volatile("s_waitcnt vmcnt(2)" ::: "memory");
    __builtin_amdgcn_s_barrier();

    int aCur = 0, aN2 = 2;   // kt%3, (kt+2)%3 (rotating, no div)
    for (int kt = 0; kt < KT32; ++kt) {
        if (kt < KT32 - 1) stageB(kt + 1, (kt + 1) & 1);
        if (kt < KT32 - 2) stageA(kt + 2, aN2);
        bf16x8 af[4], bf[4];
#pragma unroll
        for (int mi = 0; mi < 4; ++mi) af[mi] = rdA(aCur, mi);
#pragma unroll
        for (int nj = 0; nj < 4; ++nj) bf[nj] = rdB(kt & 1, nj);
        __builtin_amdgcn_s_setprio(1);
#pragma unroll
        for (int mi = 0; mi < 4; ++mi)
#pragma unroll
            for (int nj = 0; nj < 4; ++nj)
                acc[mi][nj] = __builtin_amdgcn_mfma_f32_16x16x32_bf16(
                    af[mi], bf[nj], acc[mi][nj], 0, 0, 0);
        __builtin_amdgcn_s_setprio(0);
        if (kt < KT32 - 2) { asm volatile("s_waitcnt vmcnt(2)" ::: "memory"); }
        else               { asm volatile("s_waitcnt vmcnt(0)" ::: "memory"); }
        __builtin_amdgcn_s_barrier();
        aCur = (aCur == 2) ? 0 : aCur + 1;
        aN2  = (aN2 == 2) ? 0 : aN2 + 1;
    }
}

// ---------------- fused QKV projection GEMM ----------------
// 1536 blocks (3 sel x 64 mt x 8 nt), 4/CU resident. XCD-chunked: each XCD
// owns an 8-mt stripe set; panels iterate outer so the active weight panel
// + A stripes stay L2-resident.
__global__ __launch_bounds__(256, 4) void qkv_gemm(const u16* __restrict__ q_bf,
                                                   const u16* __restrict__ kv_bf,
                                                   const u16* __restrict__ wq,
                                                   const u16* __restrict__ wk,
                                                   const u16* __restrict__ wv,
                                                   u16* __restrict__ Qh,
                                                   u16* __restrict__ Kh,
                                                   u16* __restrict__ Vt) {
    const int g = blockIdx.x;
    const int xcd = g & 7, l = g >> 3;          // l in [0,192)
    const int mt = xcd * 8 + (l & 7);           // 0..63
    const int pn = l >> 3;                      // 0..23
    const int sel = pn >> 3;                    // 0=Q 1=K 2=V
    const int m0 = mt * 128, n0 = (pn & 7) * 128;
    const u16* A = (sel == 0) ? q_bf : kv_bf;
    const u16* B = (sel == 0) ? wq : (sel == 1 ? wk : wv);

    f32x4 acc[4][4] = {};
    gcore(A, B, m0, n0, acc);

    const int t = threadIdx.x;
    const int lane = t & 63, w = t >> 6;
    const int ln = lane & 15, quad = lane >> 4;
    const int wrow = (w >> 1) * 64, wcol = (w & 1) * 64;

    if (sel == 2) {  // V: f16 transposed store Vt[(b*NH+h)*DH+d][S]
#pragma unroll
        for (int mi = 0; mi < 4; ++mi) {
            int rowb = m0 + wrow + mi * 16 + quad * 4;
            int bb = rowb >> 11, s = rowb & 2047;
#pragma unroll
            for (int ni = 0; ni < 4; ++ni) {
                int col = n0 + wcol + ni * 16 + ln;
                int h = col >> 6, d = col & 63;
                u16x4 o;
#pragma unroll
                for (int r = 0; r < 4; ++r) o[r] = f2h(acc[mi][ni][r]);
                *(u16x4*)(Vt + ((size_t)(bb * NH + h) * DH + d) * SEQ + s) = o;
            }
        }
    } else {  // Q/K: bf16 scatter to [B,H,S,Dh]; Q pre-scaled by SC_LOG2E
        u16* C = sel ? Kh : Qh;
        const float scale = sel ? 1.0f : SC_LOG2E;
#pragma unroll
        for (int mi = 0; mi < 4; ++mi) {
            int rowb = m0 + wrow + mi * 16 + quad * 4;
#pragma unroll
            for (int ni = 0; ni < 4; ++ni) {
                int col = n0 + wcol + ni * 16 + ln;
                int h = col >> 6, d = col & 63;
#pragma unroll
                for (int r = 0; r < 4; ++r) {
                    int row = rowb + r;
                    int bb = row >> 11, s = row & 2047;
                    C[((size_t)((bb * NH + h) * SEQ + s) << 6) + d] = f2bf(acc[mi][ni][r] * scale);
                }
            }
        }
    }
}

// ---------------- output projection GEMM (fp32 out) ----------------
// 512 blocks (64 mt x 8 nt).
__global__ __launch_bounds__(256, 4) void wo_gemm(const u16* __restrict__ A,
                                                  const u16* __restrict__ B,
                                                  float* __restrict__ Cout) {
    const int g = blockIdx.x;
    const int xcd = g & 7, l = g >> 3;          // l in [0,64)
    const int mt = xcd * 8 + (l & 7);           // 0..63
    const int nt = l >> 3;                      // 0..7
    const int m0 = mt * 128, n0 = nt * 128;

    f32x4 acc[4][4] = {};
    gcore(A, B, m0, n0, acc);

    const int t = threadIdx.x;
    const int lane = t & 63, w = t >> 6;
    const int ln = lane & 15, quad = lane >> 4;
    const int wrow = (w >> 1) * 64, wcol = (w & 1) * 64;

#pragma unroll
    for (int mi = 0; mi < 4; ++mi) {
        int rowb = m0 + wrow + mi * 16 + quad * 4;
#pragma unroll
        for (int ni = 0; ni < 4; ++ni) {
            int col = n0 + wcol + ni * 16 + ln;
#pragma unroll
            for (int r = 0; r < 4; ++r)
                Cout[(size_t)(rowb + r) * DM + col] = acc[mi][ni][r];
        }
    }
}

// ---------------- flash attention v5 (unchanged) ----------------
__global__ __launch_bounds__(256) void attn_kernel(const u16* __restrict__ Q,
                                                   const u16* __restrict__ K,
                                                   const u16* __restrict__ Vt,
                                                   u16* __restrict__ AO) {
    __shared__ __align__(16) u16 qs[128 * 64];  // [q][d] swizzled, 16 KB
    __shared__ __align__(16) u16 ks[64 * 64];   // [kv-permuted][d] swizzled, 8 KB
    __shared__ __align__(16) u16 vs[80 * 64];   // [d][kv] f16; rows 64-79 const, 10 KB

    const int t = threadIdx.x;
    const int lane = t & 63, w = t >> 6;
    const int ln = lane & 15, quad = lane >> 4;
    const int l3 = ln & 7;
    const int bi = blockIdx.x;            // 0..1023
    const int bh = bi & 63;
    const int qraw = bi >> 6;             // 0..15
    const int qtile = (bh & 1) ? (15 - qraw) : qraw;  // balance swizzle
    const int q0 = qtile * 128;
    const int qw0 = q0 + w * 32;
    const int ktmax = 2 * qtile + 1;
    const u16* Qb = Q + (size_t)bh * SEQ * DH;
    const u16* Kb = K + (size_t)bh * SEQ * DH;
    const u16* Vb = Vt + (size_t)bh * DH * SEQ;
    const int b = bh >> 4, h = bh & 15;

    const int cb = t & 7;          // staging col-block
    const int r0 = t >> 3;         // staging row base (0..31)
    const int swc = ((cb ^ (r0 & 7)) << 3);
    // K source-row permutation sigma(r0): bits [b4 b3 b2 b1 b0]->[b3 b2 b4 b1 b0]
    const int sg = ((r0 & 12) << 1) | ((r0 & 16) >> 2) | (r0 & 3);

    // const rows 64..79 of vs: row 64 = 1.0h (l-row), rest 0. Written once.
    if (t < 128) {
        int j = t >> 3;            // 0..15
        u16 hv = (j == 0) ? 0x3C00 : 0;
        u16x8 o = {hv, hv, hv, hv, hv, hv, hv, hv};
        *(u16x8*)&vs[((64 + j) << 6) | (((t & 7) ^ (j & 7)) << 3)] = o;
    }

    // prefetch Q tile + KV tile 0 into regs (K rows permuted by sigma)
    u16x8 qreg[4];
#pragma unroll
    for (int i = 0; i < 4; ++i)
        qreg[i] = *(const u16x8*)(Qb + (size_t)(q0 + r0 + i * 32) * DH + cb * 8);
    u16x8 kreg[2], vreg[2];
#pragma unroll
    for (int i = 0; i < 2; ++i) {
        kreg[i] = *(const u16x8*)(Kb + (size_t)(i * 32 + sg) * DH + cb * 8);
        vreg[i] = *(const u16x8*)(Vb + (size_t)(r0 + i * 32) * SEQ + cb * 8);
    }

    f32x4 oaccT[2][5] = {};

    for (int kt = 0; kt <= ktmax; ++kt) {
        const int kv0 = kt * 64;
        __syncthreads();  // all waves done reading previous tile
        if (kt == 0) {
#pragma unroll
            for (int i = 0; i < 4; ++i)
                *(u16x8*)&qs[((r0 + i * 32) << 6) | swc] = qreg[i];
        }
#pragma unroll
        for (int i = 0; i < 2; ++i) {
            *(u16x8*)&ks[((r0 + i * 32) << 6) | swc] = kreg[i];
            *(u16x8*)&vs[((r0 + i * 32) << 6) | swc] = vreg[i];
        }
        __syncthreads();  // tile published
        if (kt < ktmax) {
            const int kvn = kv0 + 64;
#pragma unroll
            for (int i = 0; i < 2; ++i) {
                kreg[i] = *(const u16x8*)(Kb + (size_t)(kvn + i * 32 + sg) * DH + cb * 8);
                vreg[i] = *(const u16x8*)(Vb + (size_t)(r0 + i * 32) * SEQ + kvn + cb * 8);
            }
        }

        if (kv0 >= qw0 + 32) continue;  // wave-uniform; barriers already done

        // ---- S^T = K Q^T : C[m=permuted kv][n=q] ----
        f32x4 st[2][4] = {};
#pragma unroll
        for (int half = 0; half < 2; ++half) {
            const int swz = (((half * 4 + quad) ^ l3) << 3);
            bf16x8 qf0 = __builtin_bit_cast(bf16x8, *(const u16x8*)&qs[((w * 32 + ln) << 6) | swz]);
            bf16x8 qf1 = __builtin_bit_cast(bf16x8, *(const u16x8*)&qs[((w * 32 + 16 + ln) << 6) | swz]);
#pragma unroll
            for (int ms = 0; ms < 4; ++ms) {
                bf16x8 kf = __builtin_bit_cast(bf16x8, *(const u16x8*)&ks[((ms * 16 + ln) << 6) | swz]);
                st[0][ms] = __builtin_amdgcn_mfma_f32_16x16x32_bf16(kf, qf0, st[0][ms], 0, 0, 0);
                st[1][ms] = __builtin_amdgcn_mfma_f32_16x16x32_bf16(kf, qf1, st[1][ms], 0, 0, 0);
            }
        }

        // ---- P = exp2(S^T); lane's value (ms,r) sits at true kv =
        //      kv0 + (ms>>1)*32 + quad*8 + (ms&1)*4 + r (sigma-permuted) ----
        half8 pf[2][2];
#pragma unroll
        for (int qt2 = 0; qt2 < 2; ++qt2) {
            const int qbase = qw0 + qt2 * 16;       // lane's q = qbase + ln
            if (kv0 + 63 > qbase) {                 // diagonal tile (wave-uniform)
                const int relq = qbase + ln - kv0 - quad * 8;
#pragma unroll
                for (int ms = 0; ms < 4; ++ms)
#pragma unroll
                    for (int r = 0; r < 4; ++r)
                        if ((ms >> 1) * 32 + (ms & 1) * 4 + r > relq)
                            st[qt2][ms][r] = -3e38f;
            }
#pragma unroll
            for (int c = 0; c < 2; ++c) {
                half2 p0 = pkrtz(__builtin_amdgcn_exp2f(st[qt2][2 * c][0]),
                                 __builtin_amdgcn_exp2f(st[qt2][2 * c][1]));
                half2 p1 = pkrtz(__builtin_amdgcn_exp2f(st[qt2][2 * c][2]),
                                 __builtin_amdgcn_exp2f(st[qt2][2 * c][3]));
                half2 p2 = pkrtz(__builtin_amdgcn_exp2f(st[qt2][2 * c + 1][0]),
                                 __builtin_amdgcn_exp2f(st[qt2][2 * c + 1][1]));
                half2 p3 = pkrtz(__builtin_amdgcn_exp2f(st[qt2][2 * c + 1][2]),
                                 __builtin_amdgcn_exp2f(st[qt2][2 * c + 1][3]));
                half8 v;
                v[0] = p0[0]; v[1] = p0[1]; v[2] = p1[0]; v[3] = p1[1];
                v[4] = p2[0]; v[5] = p2[1]; v[6] = p3[0]; v[7] = p3[1];
                pf[qt2][c] = v;
            }
        }

        // ---- O^T += V^T P^T : 16x16x32_f16, A = V^T (b128 from LDS),
        //      B = P (in-lane frags); nd=4 accumulates l via the ones-row ----
#pragma unroll
        for (int c = 0; c < 2; ++c) {
            const int off = (((c * 4 + quad) ^ l3) << 3);
#pragma unroll
            for (int nd = 0; nd < 5; ++nd) {
                half8 vf = __builtin_bit_cast(half8, *(const u16x8*)&vs[((nd * 16 + ln) << 6) | off]);
                oaccT[0][nd] = __builtin_amdgcn_mfma_f32_16x16x32_f16(vf, pf[0][c], oaccT[0][nd], 0, 0, 0);
                oaccT[1][nd] = __builtin_amdgcn_mfma_f32_16x16x32_f16(vf, pf[1][c], oaccT[1][nd], 0, 0, 0);
            }
        }
    }

    // epilogue: O^T rows = d, cols = q (= ln); l sits in quad 0's
    // oaccT[qt2][4][0] (vs row 64).
#pragma unroll
    for (int qt2 = 0; qt2 < 2; ++qt2) {
        float lv = __shfl(oaccT[qt2][4][0], ln, 64);
        float linv = 1.0f / lv;
        int q = q0 + w * 32 + qt2 * 16 + ln;
        size_t base = ((size_t)(b * SEQ + q) * DM) + h * DH + quad * 4;
#pragma unroll
        for (int nd = 0; nd < 4; ++nd) {
            u16x4 o;
#pragma unroll
            for (int r = 0; r < 4; ++r) o[r] = f2bf(oaccT[qt2][nd][r] * linv);
            *(u16x4*)&AO[base + nd * 16] = o;
        }
    }
}

// ---------------- launch ----------------
extern "C" void kernel_launch(void* const* d_in, const int* in_sizes, int n_in,
                              void* d_out, int out_size, void* d_ws, size_t ws_size,
                              hipStream_t stream) {
    const float* query = (const float*)d_in[0];
    const float* key_value = (const float*)d_in[1];
    const float* Wq = (const float*)d_in[2];
    const float* Wk = (const float*)d_in[3];
    const float* Wv = (const float*)d_in[4];
    const float* Wo = (const float*)d_in[5];
    float* out = (float*)d_out;

    char* ws = (char*)d_ws;
    const size_t SZ_ACT = (size_t)MROWS * DM * 2;  // 16 MiB
    const size_t SZ_W = (size_t)DM * DM * 2;       // 2 MiB
    u16* q_bf  = (u16*)(ws + 0);
    u16* kv_bf = (u16*)(ws + SZ_ACT);
    u16* wq_bf = (u16*)(ws + 2 * SZ_ACT);
    u16* wk_bf = (u16*)(ws + 2 * SZ_ACT + SZ_W);
    u16* wv_bf = (u16*)(ws + 2 * SZ_ACT + 2 * SZ_W);
    u16* wo_bf = (u16*)(ws + 2 * SZ_ACT + 3 * SZ_W);
    u16* Qh    = (u16*)(ws + 2 * SZ_ACT + 4 * SZ_W);              // [B,H,S,Dh] bf16 (pre-scaled)
    u16* Kh    = (u16*)(ws + 2 * SZ_ACT + 4 * SZ_W + SZ_ACT);     // [B,H,S,Dh] bf16
    u16* Vt    = (u16*)(ws + 2 * SZ_ACT + 4 * SZ_W + 2 * SZ_ACT); // [bh][64][S] f16
    u16* AOb   = q_bf;   // q_bf dead after Q projection

    const int n4_total = 2 * N4A + 4 * N4W;  // 5,242,880
    cvt_all<<<n4_total / 256, 256, 0, stream>>>(query, key_value, Wq, Wk, Wv, Wo,
                                                q_bf, kv_bf, wq_bf, wk_bf, wv_bf, wo_bf);

    qkv_gemm<<<1536, 256, 0, stream>>>(q_bf, kv_bf, wq_bf, wk_bf, wv_bf,
                                       Qh, Kh, Vt);

    attn_kernel<<<1024, 256, 0, stream>>>(Qh, Kh, Vt, AOb);

    wo_gemm<<<512, 256, 0, stream>>>(AOb, wo_bf, out);
}